// Round 1
// baseline (872.310 us; speedup 1.0000x reference)
//
#include <hip/hip_runtime.h>

#define IN_SIZE 256
#define OUT_SIZE 64
#define N_NODES 512
#define FAN_IN 32
#define T_DIM 2048
#define D_DIM 832   // IN_SIZE + N_NODES + OUT_SIZE

// ---------------------------------------------------------------------------
// Kernel 1: transpose actives (shifted by one row) into column-major actT.
// actT[c][t] = actives[t+1][c] for t in [0,2046], 0 for t == 2047.
// ---------------------------------------------------------------------------
__global__ __launch_bounds__(256) void transpose_kernel(
    const float* __restrict__ actives, float* __restrict__ actT) {
  __shared__ float tile[32][33];
  int t0 = blockIdx.x * 32;
  int c0 = blockIdx.y * 32;
  int lx = threadIdx.x;  // 0..31
  int ly = threadIdx.y;  // 0..7
#pragma unroll
  for (int i = 0; i < 4; ++i) {
    int t = t0 + ly + 8 * i;
    int c = c0 + lx;
    float v = 0.0f;
    if (t < T_DIM - 1) v = actives[(size_t)(t + 1) * D_DIM + c];
    tile[ly + 8 * i][lx] = v;
  }
  __syncthreads();
#pragma unroll
  for (int i = 0; i < 4; ++i) {
    int c = c0 + ly + 8 * i;
    int t = t0 + lx;
    actT[(size_t)c * T_DIM + t] = tile[lx][ly + 8 * i];
  }
}

// ---------------------------------------------------------------------------
// Kernel 2: per-node K/V precompute over the static 2047 timesteps (plus a
// zero t=2047 slot), interleaved float2, plus per-node k max/min.
// One block per node, 256 threads, 8 t's per thread.
// ---------------------------------------------------------------------------
__global__ __launch_bounds__(256) void kv_kernel(
    const float* __restrict__ actT, const int* __restrict__ in_idxs,
    const float* __restrict__ weights, float2* __restrict__ KV,
    float* __restrict__ kmax, float* __restrict__ kmin) {
  int ix = blockIdx.x;
  int tid = threadIdx.x;
  __shared__ int s_idx[FAN_IN];
  __shared__ float s_w1[FAN_IN], s_w2[FAN_IN];
  __shared__ float s_mx[4], s_mn[4];
  if (tid < FAN_IN) {
    s_idx[tid] = in_idxs[ix * FAN_IN + tid];
    s_w1[tid] = weights[(size_t)(ix * FAN_IN + tid) * 3 + 1];
    s_w2[tid] = weights[(size_t)(ix * FAN_IN + tid) * 3 + 2];
  }
  __syncthreads();
  float k[8], v[8];
#pragma unroll
  for (int j = 0; j < 8; ++j) { k[j] = 0.0f; v[j] = 0.0f; }
  for (int f = 0; f < FAN_IN; ++f) {
    const float* col = actT + (size_t)s_idx[f] * T_DIM;
    float w1 = s_w1[f], w2 = s_w2[f];
#pragma unroll
    for (int j = 0; j < 8; ++j) {
      float a = col[j * 256 + tid];
      k[j] = fmaf(w1, a, k[j]);
      v[j] = fmaf(w2, a, v[j]);
    }
  }
  float mx = -3.4e38f, mn = 3.4e38f;
  float2* kvb = KV + (size_t)ix * T_DIM;
#pragma unroll
  for (int j = 0; j < 8; ++j) {
    kvb[j * 256 + tid] = make_float2(k[j], v[j]);
    mx = fmaxf(mx, k[j]);
    mn = fminf(mn, k[j]);
  }
#pragma unroll
  for (int off = 32; off > 0; off >>= 1) {
    mx = fmaxf(mx, __shfl_xor(mx, off));
    mn = fminf(mn, __shfl_xor(mn, off));
  }
  int wid = tid >> 6;
  if ((tid & 63) == 0) { s_mx[wid] = mx; s_mn[wid] = mn; }
  __syncthreads();
  if (tid == 0) {
    mx = fmaxf(fmaxf(s_mx[0], s_mx[1]), fmaxf(s_mx[2], s_mx[3]));
    mn = fminf(fminf(s_mn[0], s_mn[1]), fminf(s_mn[2], s_mn[3]));
    kmax[ix] = mx;
    kmin[ix] = mn;
  }
}

// ---------------------------------------------------------------------------
// Kernel 3: sequential 512-node scan. One block, 1024 threads (16 waves).
// Last-row state lives in LDS. Wave 0 computes q/k_last/v_last; all threads
// reduce the 2048-term softmax-weighted sum (2 t's each). KV for the next
// node is prefetched (address independent of state).
// ---------------------------------------------------------------------------
__global__ __launch_bounds__(1024) void seq_kernel(
    const float* __restrict__ x, const int* __restrict__ in_idxs,
    const float* __restrict__ weights, const float2* __restrict__ KV,
    const float* __restrict__ kmax, const float* __restrict__ kmin,
    float* __restrict__ out) {
  __shared__ float lastrow[D_DIM];
  __shared__ float s_qkv[3];
  __shared__ float s_part[16][2];
  int tid = threadIdx.x;
  if (tid < D_DIM) lastrow[tid] = (tid < IN_SIZE) ? x[tid] : 0.0f;
  __syncthreads();

  float2 kv0 = KV[tid];          // prefetch node 0
  float2 kv1 = KV[tid + 1024];

  for (int ix = 0; ix < N_NODES; ++ix) {
    // --- wave 0: q, k_last, v_last (32-wide dots over LDS lastrow) ---
    if (tid < 64) {
      float p0 = 0.0f, p1 = 0.0f, p2 = 0.0f;
      if (tid < FAN_IN) {
        int idx = in_idxs[ix * FAN_IN + tid];
        float a = lastrow[idx];
        const float* wp = weights + (size_t)(ix * FAN_IN + tid) * 3;
        p0 = a * wp[0];
        p1 = a * wp[1];
        p2 = a * wp[2];
      }
#pragma unroll
      for (int off = 16; off > 0; off >>= 1) {
        p0 += __shfl_xor(p0, off);
        p1 += __shfl_xor(p1, off);
        p2 += __shfl_xor(p2, off);
      }
      if (tid == 0) { s_qkv[0] = p0; s_qkv[1] = p1; s_qkv[2] = p2; }
    }
    __syncthreads();  // (A) qkv visible to all
    float q = s_qkv[0], kl = s_qkv[1], vl = s_qkv[2];
    // exact softmax max: kmax>0>kmin (2047 gaussian samples) so this equals
    // max_t q*k_t over t<=2046; fold in the last logit q*kl.
    float m = fmaxf(fmaxf(q * kmax[ix], q * kmin[ix]), q * kl);

    float kk1 = (tid == 1023) ? kl : kv1.x;  // t = 2047 uses live k/v
    float vv1 = (tid == 1023) ? vl : kv1.y;
    float w0 = __expf(fmaf(q, kv0.x, -m));
    float w1 = __expf(fmaf(q, kk1, -m));
    float sw = w0 + w1;
    float swv = fmaf(w0, kv0.y, w1 * vv1);

    // --- prefetch next node's KV while the reduction runs ---
    int nix = (ix + 1 < N_NODES) ? (ix + 1) : ix;
    const float2* nb = KV + (size_t)nix * T_DIM;
    kv0 = nb[tid];
    kv1 = nb[tid + 1024];

    // --- two-level reduction of (sw, swv) ---
#pragma unroll
    for (int off = 32; off > 0; off >>= 1) {
      sw += __shfl_xor(sw, off);
      swv += __shfl_xor(swv, off);
    }
    int wid = tid >> 6;
    if ((tid & 63) == 0) { s_part[wid][0] = sw; s_part[wid][1] = swv; }
    __syncthreads();  // (B) partials visible to wave 0
    if (tid < 64) {
      float a = (tid < 16) ? s_part[tid][0] : 0.0f;
      float b = (tid < 16) ? s_part[tid][1] : 0.0f;
#pragma unroll
      for (int off = 8; off > 0; off >>= 1) {
        a += __shfl_xor(a, off);
        b += __shfl_xor(b, off);
      }
      if (tid == 0) {
        float o = tanhf(b / a);
        lastrow[IN_SIZE + ix] = o;  // thread 0 is in wave 0: coherent for
                                    // next iteration's wave-0 gather
        if (ix >= N_NODES - OUT_SIZE) out[ix - (N_NODES - OUT_SIZE)] = o;
      }
    }
  }
}

// ---------------------------------------------------------------------------
extern "C" void kernel_launch(void* const* d_in, const int* in_sizes, int n_in,
                              void* d_out, int out_size, void* d_ws,
                              size_t ws_size, hipStream_t stream) {
  const float* x = (const float*)d_in[0];
  const float* actives = (const float*)d_in[1];
  const float* weights = (const float*)d_in[2];
  const int* in_idxs = (const int*)d_in[3];
  float* out = (float*)d_out;

  // workspace layout (floats): actT[832][2048] | KV[512][2048] (float2) |
  // kmax[512] | kmin[512]  -> ~15.2 MB total
  float* ws = (float*)d_ws;
  const size_t ACTT_SZ = (size_t)D_DIM * T_DIM;
  const size_t KV_SZ = (size_t)N_NODES * T_DIM * 2;
  float* actT = ws;
  float2* KV = (float2*)(ws + ACTT_SZ);
  float* kmax = ws + ACTT_SZ + KV_SZ;
  float* kmin = kmax + N_NODES;

  dim3 tb(32, 8);
  dim3 tg(T_DIM / 32, D_DIM / 32);
  transpose_kernel<<<tg, tb, 0, stream>>>(actives, actT);
  kv_kernel<<<N_NODES, 256, 0, stream>>>(actT, in_idxs, weights, KV, kmax,
                                         kmin);
  seq_kernel<<<1, 1024, 0, stream>>>(x, in_idxs, weights, KV, kmax, kmin, out);
}

// Round 2
// 626.027 us; speedup vs baseline: 1.3934x; 1.3934x over previous
//
#include <hip/hip_runtime.h>

#define IN_SIZE 256
#define OUT_SIZE 64
#define N_NODES 512
#define FAN_IN 32
#define T_DIM 2048
#define D_DIM 832  // IN_SIZE + N_NODES + OUT_SIZE
#define TOTAL_EDGE (N_NODES * FAN_IN)  // 16384

// ---------------------------------------------------------------------------
// CSR inverted index build: for each j in [0,512), the list of (node, w0,w1,w2)
// whose in_idxs == 256+j. Used to scatter out_j into pending q/k/v dots.
// ---------------------------------------------------------------------------
__global__ __launch_bounds__(256) void hist_kernel(const int* __restrict__ in_idxs,
                                                   int* __restrict__ cnt) {
  int g = blockIdx.x * 256 + threadIdx.x;
  int idx = in_idxs[g];
  if (idx >= IN_SIZE) atomicAdd(&cnt[idx - IN_SIZE], 1);
}

__global__ __launch_bounds__(512) void scan_kernel(const int* __restrict__ cnt,
                                                   int* __restrict__ offs) {
  __shared__ int wtot[8];
  int tid = threadIdx.x;
  int incl = cnt[tid];
#pragma unroll
  for (int d = 1; d < 64; d <<= 1) {
    int u = __shfl_up(incl, d);
    if ((tid & 63) >= d) incl += u;
  }
  if ((tid & 63) == 63) wtot[tid >> 6] = incl;
  __syncthreads();
  int add = 0;
  for (int w = 0; w < (tid >> 6); ++w) add += wtot[w];
  offs[tid + 1] = incl + add;
  if (tid == 0) offs[0] = 0;
}

__global__ __launch_bounds__(256) void fill_kernel(
    const int* __restrict__ in_idxs, const float* __restrict__ weights,
    const int* __restrict__ offs, int* __restrict__ fillc,
    float4* __restrict__ entries) {
  int g = blockIdx.x * 256 + threadIdx.x;
  int idx = in_idxs[g];
  if (idx >= IN_SIZE) {
    int j = idx - IN_SIZE;
    int p = atomicAdd(&fillc[j], 1);
    int node = g >> 5;
    const float* wp = weights + (size_t)g * 3;
    entries[offs[j] + p] = make_float4(__int_as_float(node), wp[0], wp[1], wp[2]);
  }
}

// ---------------------------------------------------------------------------
// Base dots from x (lastrow positions >= IN_SIZE are 0 at init).
// 8 nodes per block, 32 lanes per node.
// ---------------------------------------------------------------------------
__global__ __launch_bounds__(256) void base_kernel(
    const float* __restrict__ x, const int* __restrict__ in_idxs,
    const float* __restrict__ weights, float4* __restrict__ Qb) {
  int tid = threadIdx.x;
  int node = blockIdx.x * 8 + (tid >> 5);
  int f = tid & 31;
  int g = node * FAN_IN + f;
  int idx = in_idxs[g];
  float a = (idx < IN_SIZE) ? x[idx] : 0.f;
  const float* wp = weights + (size_t)g * 3;
  float p0 = a * wp[0], p1 = a * wp[1], p2 = a * wp[2];
#pragma unroll
  for (int off = 16; off > 0; off >>= 1) {
    p0 += __shfl_xor(p0, off);
    p1 += __shfl_xor(p1, off);
    p2 += __shfl_xor(p2, off);
  }
  if (f == 0) Qb[node] = make_float4(p0, p1, p2, 0.f);
}

// ---------------------------------------------------------------------------
// Fused KV build, t-major: stage 8 shifted activation rows in LDS, gather for
// all 512 nodes from LDS. KV[node][t] = (k,v); t=2047 slot zeroed.
// ---------------------------------------------------------------------------
__global__ __launch_bounds__(256) void kv_build_kernel(
    const float* __restrict__ actives, const int* __restrict__ in_idxs,
    const float* __restrict__ weights, float2* __restrict__ KV) {
  __shared__ float rows[8][833];  // pad 833: bank varies with row
  __shared__ int s_idx[64 * FAN_IN];
  __shared__ float2 s_w[64 * FAN_IN];
  int tid = threadIdx.x;
  int tb = blockIdx.x * 8;
  for (int i = tid; i < 8 * D_DIM; i += 256) {
    int r = i / D_DIM, c = i - r * D_DIM;
    int t = tb + r;
    rows[r][c] = (t < T_DIM - 1) ? actives[(size_t)(t + 1) * D_DIM + c] : 0.f;
  }
  int tl = tid & 7, ng = tid >> 3;
  for (int tile = 0; tile < 8; ++tile) {
    __syncthreads();  // protect s_idx/s_w reuse (and rows fill on tile 0)
    int n0 = tile * 64;
    for (int i = tid; i < 64 * FAN_IN; i += 256) {
      int g = n0 * FAN_IN + i;
      s_idx[i] = in_idxs[g];
      const float* wp = weights + (size_t)g * 3;
      s_w[i] = make_float2(wp[1], wp[2]);
    }
    __syncthreads();
#pragma unroll
    for (int it = 0; it < 2; ++it) {
      int nl = ng + 32 * it;
      const int* ip = &s_idx[nl * FAN_IN];
      const float2* wp = &s_w[nl * FAN_IN];
      float k = 0.f, v = 0.f;
#pragma unroll 8
      for (int f = 0; f < FAN_IN; ++f) {
        float a = rows[tl][ip[f]];
        float2 w = wp[f];
        k = fmaf(w.x, a, k);
        v = fmaf(w.y, a, v);
      }
      KV[(size_t)(n0 + nl) * T_DIM + tb + tl] = make_float2(k, v);
    }
  }
}

// ---------------------------------------------------------------------------
// Per-node k max/min (for exact softmax max: kmax>0>kmin; includes the zero
// t=2047 slot which is harmless).
// ---------------------------------------------------------------------------
__global__ __launch_bounds__(256) void kminmax_kernel(const float2* __restrict__ KV,
                                                      float2* __restrict__ kmm) {
  int ix = blockIdx.x, tid = threadIdx.x;
  const float2* b = KV + (size_t)ix * T_DIM;
  float mx = -3.4e38f, mn = 3.4e38f;
  for (int t = tid; t < T_DIM; t += 256) {
    float k = b[t].x;
    mx = fmaxf(mx, k);
    mn = fminf(mn, k);
  }
#pragma unroll
  for (int off = 32; off > 0; off >>= 1) {
    mx = fmaxf(mx, __shfl_xor(mx, off));
    mn = fminf(mn, __shfl_xor(mn, off));
  }
  __shared__ float smx[4], smn[4];
  if ((tid & 63) == 0) { smx[tid >> 6] = mx; smn[tid >> 6] = mn; }
  __syncthreads();
  if (tid == 0) {
    mx = fmaxf(fmaxf(smx[0], smx[1]), fmaxf(smx[2], smx[3]));
    mn = fminf(fminf(smn[0], smn[1]), fminf(smn[2], smn[3]));
    kmm[ix] = make_float2(mx, mn);
  }
}

// ---------------------------------------------------------------------------
// Sequential scan: 1 block x 256 threads (4 waves). Pending (q,kl,vl) per node
// live in LDS, updated by scatter when each output is produced. Per step:
// LDS read -> 8 exp/lane -> wave reduce -> barrier -> redundant finish ->
// scatter atomicAdds -> barrier. KV + scatter entries prefetched (state-
// independent addresses), drained by the barriers.
// ---------------------------------------------------------------------------
__global__ __launch_bounds__(256) void seq_kernel(
    const float4* __restrict__ Qb, const float2* __restrict__ kmm_g,
    const int* __restrict__ offs_g, const float4* __restrict__ entries,
    const float2* __restrict__ KV, float* __restrict__ out) {
  __shared__ float4 sQKV[N_NODES];   // x=q, y=kl, z=vl pending dots
  __shared__ float2 skmm[N_NODES];
  __shared__ int soffs[N_NODES + 1];
  __shared__ float2 spart[4];
  __shared__ float souts[OUT_SIZE];
  int tid = threadIdx.x;
  for (int i = tid; i < N_NODES; i += 256) {
    sQKV[i] = Qb[i];
    skmm[i] = kmm_g[i];
  }
  for (int i = tid; i <= N_NODES; i += 256) soffs[i] = offs_g[i];
  __syncthreads();

  float2 kv[8];
#pragma unroll
  for (int j = 0; j < 8; ++j) kv[j] = KV[tid + 256 * j];  // node 0

  for (int ix = 0; ix < N_NODES; ++ix) {
    float4 qkv = sQKV[ix];  // visible: barrier B2 of previous step
    float2 mm = skmm[ix];
    float q = qkv.x, kl = qkv.y, vl = qkv.z;
    int off0 = soffs[ix], cnt = soffs[ix + 1] - off0;

    // prefetch this node's scatter entries + next node's KV (off critical path)
    float4 ent;
    if (tid < cnt) ent = entries[off0 + tid];
    int nix = (ix + 1 < N_NODES) ? ix + 1 : ix;
    const float2* nb = KV + (size_t)nix * T_DIM;
    float2 kvn[8];
#pragma unroll
    for (int j = 0; j < 8; ++j) kvn[j] = nb[tid + 256 * j];

    // exact softmax max (kmax>0>kmin over 2047 gaussian k's) + live term
    float m = fmaxf(fmaxf(q * mm.x, q * mm.y), q * kl);
    float sw = 0.f, swv = 0.f;
#pragma unroll
    for (int j = 0; j < 8; ++j) {
      float kk = kv[j].x, vv = kv[j].y;
      if (j == 7 && tid == 255) { kk = kl; vv = vl; }  // t = 2047 live k/v
      float w = __expf(fmaf(q, kk, -m));
      sw += w;
      swv = fmaf(w, vv, swv);
    }
#pragma unroll
    for (int off = 1; off < 64; off <<= 1) {
      sw += __shfl_xor(sw, off);
      swv += __shfl_xor(swv, off);
    }
    if ((tid & 63) == 0) spart[tid >> 6] = make_float2(sw, swv);
    __syncthreads();  // B1: partials + prefetches drained

    // every thread finishes redundantly (no second broadcast needed)
    float4 pa = *(const float4*)&spart[0];
    float4 pb = *(const float4*)&spart[2];
    float S = pa.x + pa.z + pb.x + pb.z;
    float SV = pa.y + pa.w + pb.y + pb.w;
    float z = SV / S;                 // S >= 1 (max term is exp(0)=1)
    float e = __expf(2.f * z);
    float o = 1.f - 2.f / (e + 1.f);  // tanh; e=inf -> 1, e->0 -> -1

    if (tid == 0 && ix >= N_NODES - OUT_SIZE) souts[ix - (N_NODES - OUT_SIZE)] = o;

    // scatter out_ix into pending dots of future nodes
    if (tid < cnt) {
      int n = __float_as_int(ent.x);
      atomicAdd(&sQKV[n].x, o * ent.y);
      atomicAdd(&sQKV[n].y, o * ent.z);
      atomicAdd(&sQKV[n].z, o * ent.w);
    }
    for (int e2 = tid + 256; e2 < cnt; e2 += 256) {  // cnt>256 ~impossible, safe
      float4 ee = entries[off0 + e2];
      int n = __float_as_int(ee.x);
      atomicAdd(&sQKV[n].x, o * ee.y);
      atomicAdd(&sQKV[n].y, o * ee.z);
      atomicAdd(&sQKV[n].z, o * ee.w);
    }
#pragma unroll
    for (int j = 0; j < 8; ++j) kv[j] = kvn[j];
    __syncthreads();  // B2: scatter visible for next step
  }
  if (tid < OUT_SIZE) out[tid] = souts[tid];
}

// ---------------------------------------------------------------------------
extern "C" void kernel_launch(void* const* d_in, const int* in_sizes, int n_in,
                              void* d_out, int out_size, void* d_ws,
                              size_t ws_size, hipStream_t stream) {
  const float* x = (const float*)d_in[0];
  const float* actives = (const float*)d_in[1];
  const float* weights = (const float*)d_in[2];
  const int* in_idxs = (const int*)d_in[3];
  float* out = (float*)d_out;

  // workspace layout (~8.7 MB)
  char* ws = (char*)d_ws;
  float2* KV = (float2*)ws;                        // 8,388,608 B
  float4* entries = (float4*)(ws + 8388608);       // 262,144 B
  float4* Qb = (float4*)(ws + 8388608 + 262144);   // 8,192 B
  float2* kmm = (float2*)(ws + 8388608 + 262144 + 8192);  // 4,096 B
  int* cnt = (int*)(ws + 8388608 + 262144 + 8192 + 4096); // 2,048 B
  int* fillc = cnt + N_NODES;                      // 2,048 B
  int* offs = fillc + N_NODES;                     // 2,052 B

  hipMemsetAsync(cnt, 0, 2 * N_NODES * sizeof(int), stream);  // cnt + fillc
  hist_kernel<<<TOTAL_EDGE / 256, 256, 0, stream>>>(in_idxs, cnt);
  scan_kernel<<<1, 512, 0, stream>>>(cnt, offs);
  fill_kernel<<<TOTAL_EDGE / 256, 256, 0, stream>>>(in_idxs, weights, offs,
                                                    fillc, entries);
  base_kernel<<<N_NODES / 8, 256, 0, stream>>>(x, in_idxs, weights, Qb);
  kv_build_kernel<<<T_DIM / 8, 256, 0, stream>>>(actives, in_idxs, weights, KV);
  kminmax_kernel<<<N_NODES, 256, 0, stream>>>(KV, kmm);
  seq_kernel<<<1, 256, 0, stream>>>(Qb, kmm, offs, entries, KV, out);
}

// Round 3
// 503.662 us; speedup vs baseline: 1.7319x; 1.2430x over previous
//
#include <hip/hip_runtime.h>

#define IN_SIZE 256
#define OUT_SIZE 64
#define N_NODES 512
#define FAN_IN 32
#define T_DIM 2048
#define D_DIM 832  // IN_SIZE + N_NODES + OUT_SIZE
#define TOTAL_EDGE (N_NODES * FAN_IN)  // 16384

// ---------------------------------------------------------------------------
// DPP wave64 sum helpers (canonical GCN pattern; lane 63 ends with the total)
// ---------------------------------------------------------------------------
template <int CTRL, int RM>
__device__ __forceinline__ float dppadd(float v) {
  int m = __builtin_amdgcn_update_dpp(0, __float_as_int(v), CTRL, RM, 0xf, true);
  return v + __int_as_float(m);
}
__device__ __forceinline__ void wave_sum2(float& a, float& b) {
  a = dppadd<0x111, 0xf>(a); b = dppadd<0x111, 0xf>(b);  // row_shr:1
  a = dppadd<0x112, 0xf>(a); b = dppadd<0x112, 0xf>(b);  // row_shr:2
  a = dppadd<0x114, 0xf>(a); b = dppadd<0x114, 0xf>(b);  // row_shr:4
  a = dppadd<0x118, 0xf>(a); b = dppadd<0x118, 0xf>(b);  // row_shr:8
  a = dppadd<0x142, 0xa>(a); b = dppadd<0x142, 0xa>(b);  // row_bcast:15
  a = dppadd<0x143, 0xc>(a); b = dppadd<0x143, 0xc>(b);  // row_bcast:31
}
__device__ __forceinline__ float rl63(float v) {
  return __int_as_float(__builtin_amdgcn_readlane(__float_as_int(v), 63));
}

// ---------------------------------------------------------------------------
// Inverted index (distance>=2 only; distance-1 handled by register patch)
// ---------------------------------------------------------------------------
__global__ __launch_bounds__(256) void hist_kernel(const int* __restrict__ in_idxs,
                                                   int* __restrict__ cnt) {
  int g = blockIdx.x * 256 + threadIdx.x;
  int idx = in_idxs[g];
  int node = g >> 5;
  if (idx >= IN_SIZE) {
    int j = idx - IN_SIZE;
    if (j != node - 1) atomicAdd(&cnt[j], 1);
  }
}

__global__ __launch_bounds__(512) void scan_kernel(const int* __restrict__ cnt,
                                                   int* __restrict__ offs) {
  __shared__ int wtot[8];
  int tid = threadIdx.x;
  int incl = cnt[tid];
#pragma unroll
  for (int d = 1; d < 64; d <<= 1) {
    int u = __shfl_up(incl, d);
    if ((tid & 63) >= d) incl += u;
  }
  if ((tid & 63) == 63) wtot[tid >> 6] = incl;
  __syncthreads();
  int add = 0;
  for (int w = 0; w < (tid >> 6); ++w) add += wtot[w];
  offs[tid + 1] = incl + add;
  if (tid == 0) offs[0] = 0;
}

__global__ __launch_bounds__(256) void fill_kernel(
    const int* __restrict__ in_idxs, const float* __restrict__ weights,
    const int* __restrict__ offs, int* __restrict__ fillc,
    float4* __restrict__ entries) {
  int g = blockIdx.x * 256 + threadIdx.x;
  int idx = in_idxs[g];
  int node = g >> 5;
  if (idx >= IN_SIZE) {
    int j = idx - IN_SIZE;
    if (j != node - 1) {
      int p = atomicAdd(&fillc[j], 1);
      const float* wp = weights + (size_t)g * 3;
      entries[offs[j] + p] =
          make_float4(__int_as_float(node), wp[0], wp[1], wp[2]);
    }
  }
}

// ---------------------------------------------------------------------------
// Base dots from x + adjw (distance-1 patch weights): adjw[n] = sum of weights
// over edges of node n with idx == 256 + (n-1).
// ---------------------------------------------------------------------------
__global__ __launch_bounds__(256) void base_kernel(
    const float* __restrict__ x, const int* __restrict__ in_idxs,
    const float* __restrict__ weights, float4* __restrict__ Qb,
    float4* __restrict__ adjw) {
  int tid = threadIdx.x;
  int node = blockIdx.x * 8 + (tid >> 5);
  int f = tid & 31;
  int g = node * FAN_IN + f;
  int idx = in_idxs[g];
  const float* wp = weights + (size_t)g * 3;
  float a = (idx < IN_SIZE) ? x[idx] : 0.f;
  bool d1 = (idx >= IN_SIZE) && (idx - IN_SIZE == node - 1);
  float p0 = a * wp[0], p1 = a * wp[1], p2 = a * wp[2];
  float p3 = d1 ? wp[0] : 0.f, p4 = d1 ? wp[1] : 0.f, p5 = d1 ? wp[2] : 0.f;
#pragma unroll
  for (int off = 16; off > 0; off >>= 1) {
    p0 += __shfl_xor(p0, off);
    p1 += __shfl_xor(p1, off);
    p2 += __shfl_xor(p2, off);
    p3 += __shfl_xor(p3, off);
    p4 += __shfl_xor(p4, off);
    p5 += __shfl_xor(p5, off);
  }
  if (f == 0) {
    Qb[node] = make_float4(p0, p1, p2, 0.f);
    adjw[node] = make_float4(p3, p4, p5, 0.f);
  }
}

// ---------------------------------------------------------------------------
// Fused KV build (t-major, rows staged in LDS). Slot 2047 written zero
// (excluded later by bucketing anyway).
// ---------------------------------------------------------------------------
__global__ __launch_bounds__(256) void kv_build_kernel(
    const float* __restrict__ actives, const int* __restrict__ in_idxs,
    const float* __restrict__ weights, float2* __restrict__ KV) {
  __shared__ float rows[8][833];
  __shared__ int s_idx[64 * FAN_IN];
  __shared__ float2 s_w[64 * FAN_IN];
  int tid = threadIdx.x;
  int tb = blockIdx.x * 8;
  for (int i = tid; i < 8 * D_DIM; i += 256) {
    int r = i / D_DIM, c = i - r * D_DIM;
    int t = tb + r;
    rows[r][c] = (t < T_DIM - 1) ? actives[(size_t)(t + 1) * D_DIM + c] : 0.f;
  }
  int tl = tid & 7, ng = tid >> 3;
  for (int tile = 0; tile < 8; ++tile) {
    __syncthreads();
    int n0 = tile * 64;
    for (int i = tid; i < 64 * FAN_IN; i += 256) {
      int g = n0 * FAN_IN + i;
      s_idx[i] = in_idxs[g];
      const float* wp = weights + (size_t)g * 3;
      s_w[i] = make_float2(wp[1], wp[2]);
    }
    __syncthreads();
#pragma unroll
    for (int it = 0; it < 2; ++it) {
      int nl = ng + 32 * it;
      const int* ip = &s_idx[nl * FAN_IN];
      const float2* wp = &s_w[nl * FAN_IN];
      float k = 0.f, v = 0.f;
#pragma unroll 8
      for (int f = 0; f < FAN_IN; ++f) {
        float a = rows[tl][ip[f]];
        float2 w = wp[f];
        k = fmaf(w.x, a, k);
        v = fmaf(w.y, a, v);
      }
      KV[(size_t)(n0 + nl) * T_DIM + tb + tl] = make_float2(k, v);
    }
  }
}

// ---------------------------------------------------------------------------
// Bucket the 2047 static (k,v) pairs per node into 64 k-bins, ascending by
// bin (order within bin irrelevant). Slot 2047 unwritten/unused. Also exact
// kmax/kmin per node.
// ---------------------------------------------------------------------------
__global__ __launch_bounds__(256) void bucket_kernel(
    const float2* __restrict__ KV, float2* __restrict__ Bout,
    float2* __restrict__ kmm) {
  __shared__ float2 skv[2048];
  __shared__ int hist[64];
  __shared__ float smx[4], smn[4];
  int node = blockIdx.x, tid = threadIdx.x;
  const float2* src = KV + (size_t)node * T_DIM;
  float mx = -3.4e38f, mn = 3.4e38f;
#pragma unroll
  for (int j = 0; j < 8; ++j) {
    int t = j * 256 + tid;
    float2 kv = src[t];
    skv[t] = kv;
    if (t < 2047) { mx = fmaxf(mx, kv.x); mn = fminf(mn, kv.x); }
  }
  if (tid < 64) hist[tid] = 0;
#pragma unroll
  for (int off = 32; off > 0; off >>= 1) {
    mx = fmaxf(mx, __shfl_xor(mx, off));
    mn = fminf(mn, __shfl_xor(mn, off));
  }
  if ((tid & 63) == 0) { smx[tid >> 6] = mx; smn[tid >> 6] = mn; }
  __syncthreads();
  float kmax = fmaxf(fmaxf(smx[0], smx[1]), fmaxf(smx[2], smx[3]));
  float kmin = fminf(fminf(smn[0], smn[1]), fminf(smn[2], smn[3]));
  float invbw = 64.0f / (kmax - kmin);
#pragma unroll
  for (int j = 0; j < 8; ++j) {
    int t = j * 256 + tid;
    if (t < 2047) {
      int b = (int)((skv[t].x - kmin) * invbw);
      b = b < 0 ? 0 : (b > 63 ? 63 : b);
      atomicAdd(&hist[b], 1);
    }
  }
  __syncthreads();
  if (tid < 64) {
    int v = hist[tid];
    int incl = v;
#pragma unroll
    for (int d = 1; d < 64; d <<= 1) {
      int u = __shfl_up(incl, d);
      if (tid >= d) incl += u;
    }
    hist[tid] = incl - v;  // exclusive prefix -> running cursor
  }
  __syncthreads();
  float2* dst = Bout + (size_t)node * T_DIM;
#pragma unroll
  for (int j = 0; j < 8; ++j) {
    int t = j * 256 + tid;
    if (t < 2047) {
      int b = (int)((skv[t].x - kmin) * invbw);
      b = b < 0 ? 0 : (b > 63 ? 63 : b);
      int p = atomicAdd(&hist[b], 1);
      dst[p] = skv[t];
    }
  }
  if (tid == 0) kmm[node] = make_float2(kmax, kmin);
}

// ---------------------------------------------------------------------------
// Sequential scan: ONE wave (64 threads), zero barriers in the main loop.
// - early LDS read of next node's pending dot (misses only the d1 term,
//   patched in registers with adjw) -> LDS latency fully hidden
// - DPP reduction (lane 63 collects)
// - bucketed KV + early exit: usually only 512 of 2047 terms evaluated
// - chunk-0 for both read directions prefetched 2 nodes ahead
// ---------------------------------------------------------------------------
__global__ __launch_bounds__(64) void seq_kernel(
    const float4* __restrict__ Qb, const float2* __restrict__ kmm_g,
    const int* __restrict__ offs_g, const float4* __restrict__ adjw_g,
    const float4* __restrict__ entries, const float2* __restrict__ Bkv,
    float* __restrict__ out) {
  __shared__ float4 sQKV[N_NODES];
  __shared__ float2 skmm[N_NODES];
  __shared__ float4 sAdj[N_NODES];
  __shared__ int soffs[N_NODES + 1];
  const int lane = threadIdx.x;
  for (int i = lane; i < N_NODES; i += 64) {
    sQKV[i] = Qb[i];
    skmm[i] = kmm_g[i];
    sAdj[i] = adjw_g[i];
  }
  for (int i = lane; i <= N_NODES; i += 64) soffs[i] = offs_g[i];
  __syncthreads();

  const int abase = 8 * lane;         // ascending chunk-0 base slot
  const int dbase = 2040 - 8 * lane;  // descending chunk-0 base slot

  float4 bufA[2][4], bufB[2][4];
  {
    const float4* p0a = (const float4*)(Bkv + abase);
    const float4* p0d = (const float4*)(Bkv + dbase);
    const float4* p1a = (const float4*)(Bkv + T_DIM + abase);
    const float4* p1d = (const float4*)(Bkv + T_DIM + dbase);
#pragma unroll
    for (int f = 0; f < 4; ++f) {
      bufA[0][f] = p0a[f]; bufA[1][f] = p0d[f];
      bufB[0][f] = p1a[f]; bufB[1][f] = p1d[f];
    }
  }
  float4 qkv = sQKV[0];
  float2 mmx = skmm[0];
  int off_cur = soffs[1];  // soffs[ix+1]
  int cnt_cur = off_cur;   // soffs[1] - soffs[0]
  float4 entc = entries[lane];

  auto step = [&](int ix, float4(&cur)[2][4], float4(&nxt)[2][4]) {
    (void)nxt;
    int ixn = (ix + 1 < N_NODES) ? ix + 1 : N_NODES - 1;
    int ix2 = (ix + 2 < N_NODES) ? ix + 2 : N_NODES - 1;
    // early LDS reads: latency hidden by this whole step. Safe: step-s
    // scatters target nodes >= s+2, so sQKV[ix+1] is final except for the
    // d1 term (o_ix * adjw), patched below.
    float4 rawn = sQKV[ixn];
    float2 kmmn = skmm[ixn];
    float4 adjn = sAdj[ixn];
    int off_n1 = soffs[(ix + 2 <= N_NODES) ? (ix + 2) : N_NODES];
    float4 entn = entries[off_cur + lane];  // entries for node ix+1

    float q = qkv.x, kl = qkv.y, vl = qkv.z;
    bool asc = (q < 0.0f);
    float m = fmaxf(fmaxf(q * mmx.x, q * mmx.y), q * kl);
    float el = __expf(q * kl - m);

    float sw = 0.f, swv = 0.f;
    float kb0 = 0.f, kb7 = 0.f;
#pragma unroll
    for (int f = 0; f < 4; ++f) {
      float4 e0 = cur[0][f], e1 = cur[1][f];
      float4 e = make_float4(asc ? e0.x : e1.x, asc ? e0.y : e1.y,
                             asc ? e0.z : e1.z, asc ? e0.w : e1.w);
      float w0 = __expf(fmaf(q, e.x, -m));
      float w1 = __expf(fmaf(q, e.z, -m));
      if (f == 3 && !asc && lane == 0) w1 = 0.f;  // slot 2047 (invalid)
      sw += w0 + w1;
      swv = fmaf(w0, e.y, fmaf(w1, e.w, swv));
      if (f == 0) kb0 = e.x;
      if (f == 3) kb7 = e.z;
    }
    float kmaxv = mmx.x, kminv = mmx.y;
    float bw = (kmaxv - kminv) * 0.015625f;
    float invbw = 64.0f / (kmaxv - kminv);
    {
      float kb = rl63(asc ? kb7 : kb0);
      int bb = (int)((kb - kminv) * invbw);
      bb = bb < 0 ? 0 : (bb > 63 ? 63 : bb);
      float edge = kminv + (bb + (asc ? 0 : 1)) * bw;
      if (q * edge - m >= -24.0f) {
        // tail chunks (rare: ~19% of nodes) — dropped mass < 2047*e^-24
        const float2* nb = Bkv + (size_t)ix * T_DIM;
        float4 t[4];
        {
          int base = asc ? (abase + 512) : (dbase - 512);
          const float4* p = (const float4*)(nb + base);
#pragma unroll
          for (int f = 0; f < 4; ++f) t[f] = p[f];
        }
        int c = 1;
        while (true) {
          float4 u[4];
          if (c < 3) {
            int base = asc ? (abase + 512 * (c + 1)) : (dbase - 512 * (c + 1));
            const float4* p = (const float4*)(nb + base);
#pragma unroll
            for (int f = 0; f < 4; ++f) u[f] = p[f];
          }
          float ckb0 = 0.f, ckb7 = 0.f;
#pragma unroll
          for (int f = 0; f < 4; ++f) {
            float4 e = t[f];
            float w0 = __expf(fmaf(q, e.x, -m));
            float w1 = __expf(fmaf(q, e.z, -m));
            if (f == 3 && c == 3 && asc && lane == 63) w1 = 0.f;  // slot 2047
            sw += w0 + w1;
            swv = fmaf(w0, e.y, fmaf(w1, e.w, swv));
            if (f == 0) ckb0 = e.x;
            if (f == 3) ckb7 = e.z;
          }
          if (c == 3) break;
          float ckb = rl63(asc ? ckb7 : ckb0);
          int b2 = (int)((ckb - kminv) * invbw);
          b2 = b2 < 0 ? 0 : (b2 > 63 ? 63 : b2);
          float ed = kminv + (b2 + (asc ? 0 : 1)) * bw;
          if (q * ed - m < -24.0f) break;
#pragma unroll
          for (int f = 0; f < 4; ++f) t[f] = u[f];
          ++c;
        }
      }
    }
    // cur regs are dead now: issue 2-ahead prefetch (both dirs) for ix+2
    {
      const float4* pa = (const float4*)(Bkv + (size_t)ix2 * T_DIM + abase);
      const float4* pd = (const float4*)(Bkv + (size_t)ix2 * T_DIM + dbase);
#pragma unroll
      for (int f = 0; f < 4; ++f) { cur[0][f] = pa[f]; cur[1][f] = pd[f]; }
    }
    // reduce + finish
    wave_sum2(sw, swv);
    float S = rl63(sw) + el;
    float SV = fmaf(el, vl, rl63(swv));
    float z = SV * __builtin_amdgcn_rcpf(S);
    float eo = __expf(2.0f * z);
    float o = 1.0f - 2.0f * __builtin_amdgcn_rcpf(eo + 1.0f);
    if (lane == 0 && ix >= N_NODES - OUT_SIZE) out[ix - (N_NODES - OUT_SIZE)] = o;
    // scatter (distance >= 2 only); visible to reads from step ix+1 on
    if (lane < cnt_cur) {
      int n = __float_as_int(entc.x);
      atomicAdd(&sQKV[n].x, o * entc.y);
      atomicAdd(&sQKV[n].y, o * entc.z);
      atomicAdd(&sQKV[n].z, o * entc.w);
    }
    for (int e2 = lane + 64; e2 < cnt_cur; e2 += 64) {  // overflow: rare
      float4 ee = entries[soffs[ix] + e2];
      int n = __float_as_int(ee.x);
      atomicAdd(&sQKV[n].x, o * ee.y);
      atomicAdd(&sQKV[n].y, o * ee.z);
      atomicAdd(&sQKV[n].z, o * ee.w);
    }
    // rotate state; d1 register patch completes node ix+1's pending dot
    qkv = make_float4(rawn.x + o * adjn.x, rawn.y + o * adjn.y,
                      rawn.z + o * adjn.z, 0.f);
    mmx = kmmn;
    cnt_cur = off_n1 - off_cur;
    off_cur = off_n1;
    entc = entn;
  };

  for (int ix = 0; ix < N_NODES; ix += 2) {
    step(ix, bufA, bufB);
    step(ix + 1, bufB, bufA);
  }
}

// ---------------------------------------------------------------------------
extern "C" void kernel_launch(void* const* d_in, const int* in_sizes, int n_in,
                              void* d_out, int out_size, void* d_ws,
                              size_t ws_size, hipStream_t stream) {
  const float* x = (const float*)d_in[0];
  const float* actives = (const float*)d_in[1];
  const float* weights = (const float*)d_in[2];
  const int* in_idxs = (const int*)d_in[3];
  float* out = (float*)d_out;

  // workspace layout (~17.1 MB)
  char* ws = (char*)d_ws;
  float2* KV = (float2*)ws;                         // 8,388,608 B (raw, t-order)
  float2* Bkv = (float2*)(ws + 8388608);            // 8,388,608 B (bucketed)
  size_t off = 8388608u + 8388608u;
  float4* entries = (float4*)(ws + off); off += (TOTAL_EDGE + 64) * 16;
  float4* Qb = (float4*)(ws + off);      off += N_NODES * 16;
  float4* adjw = (float4*)(ws + off);    off += N_NODES * 16;
  float2* kmm = (float2*)(ws + off);     off += N_NODES * 8;
  int* cnt = (int*)(ws + off);           off += N_NODES * 4;
  int* fillc = (int*)(ws + off);         off += N_NODES * 4;
  int* offs = (int*)(ws + off);

  hipMemsetAsync(cnt, 0, 2 * N_NODES * sizeof(int), stream);  // cnt + fillc
  hist_kernel<<<TOTAL_EDGE / 256, 256, 0, stream>>>(in_idxs, cnt);
  scan_kernel<<<1, 512, 0, stream>>>(cnt, offs);
  fill_kernel<<<TOTAL_EDGE / 256, 256, 0, stream>>>(in_idxs, weights, offs,
                                                    fillc, entries);
  base_kernel<<<N_NODES / 8, 256, 0, stream>>>(x, in_idxs, weights, Qb, adjw);
  kv_build_kernel<<<T_DIM / 8, 256, 0, stream>>>(actives, in_idxs, weights, KV);
  bucket_kernel<<<N_NODES, 256, 0, stream>>>(KV, Bkv, kmm);
  seq_kernel<<<1, 64, 0, stream>>>(Qb, kmm, offs, adjw, entries, Bkv, out);
}